// Round 10
// baseline (291.083 us; speedup 1.0000x reference)
//
#include <hip/hip_runtime.h>
#include <hip/hip_bf16.h>

// GraphSAGE forward. R9: gather with coalesced eidx prefetch + 8-deep row-load
// pipelining; pool+head fused into tail_kernel (binary-search segments, no
// atomics); pscan folded into scan2 (each block derives its own prefix).
// 10 dispatches: memset, prep, psum, scan2, fill, gemm1, gather1, gemm2,
// gather2, tail.

#define HID 256
#define NCOL 512

typedef __bf16 bf16x8 __attribute__((ext_vector_type(8)));
typedef float floatx4 __attribute__((ext_vector_type(4)));
typedef unsigned int u32;
typedef const u32 __attribute__((address_space(1)))* gp_t;
typedef u32 __attribute__((address_space(3)))* lp_t;

__device__ __forceinline__ ushort f2bf(float f) {   // round-to-nearest-even
    unsigned u = __float_as_uint(f);
    u += 0x7fffu + ((u >> 16) & 1u);
    return (ushort)(u >> 16);
}
__device__ __forceinline__ float bf2f(ushort b) {
    return __uint_as_float(((unsigned)b) << 16);
}

// ---------------- fused prep: [cvt x->bf16 | packT W1 | packT W2 | degree histogram]
__device__ __forceinline__ void packT_work(const float* __restrict__ Wn,
                                           const float* __restrict__ Ws,
                                           ushort* __restrict__ WT, int K, int gid) {
    if (gid >= NCOL * K) return;
    int n = gid / K, k = gid - n * K;
    float v = (n < HID) ? Wn[k * HID + n] : Ws[k * HID + (n - HID)];
    WT[gid] = f2bf(v);
}

__global__ void prep_kernel(const float* __restrict__ x, ushort* __restrict__ xb, int n4,
                            const float* __restrict__ W1n, const float* __restrict__ W1s,
                            ushort* __restrict__ w1t, int K1,
                            const float* __restrict__ W2n, const float* __restrict__ W2s,
                            ushort* __restrict__ w2t, int K2,
                            const int* __restrict__ dst, int* __restrict__ degi, int n_edges,
                            int nb_cvt, int nb_w1, int nb_w2) {
    int bx = blockIdx.x, t = threadIdx.x;
    if (bx < nb_cvt) {
        int i = bx * 256 + t;
        if (i < n4) {
            float4 v = ((const float4*)x)[i];
            ushort4 o;
            o.x = f2bf(v.x); o.y = f2bf(v.y); o.z = f2bf(v.z); o.w = f2bf(v.w);
            ((ushort4*)xb)[i] = o;
        }
    } else if (bx < nb_cvt + nb_w1) {
        packT_work(W1n, W1s, w1t, K1, (bx - nb_cvt) * 256 + t);
    } else if (bx < nb_cvt + nb_w1 + nb_w2) {
        packT_work(W2n, W2s, w2t, K2, (bx - nb_cvt - nb_w1) * 256 + t);
    } else {
        int e = (bx - nb_cvt - nb_w1 - nb_w2) * 256 + t;
        if (e < n_edges) atomicAdd(&degi[dst[e]], 1);
    }
}

// ---------------- scan phase 1: per-256-chunk sums
__global__ __launch_bounds__(256) void psum_kernel(const int* __restrict__ degi,
                                                   int* __restrict__ partials, int n) {
    int t = threadIdx.x;
    int i = blockIdx.x * 256 + t;
    int v = (i < n) ? degi[i] : 0;
#pragma unroll
    for (int d = 1; d < 64; d <<= 1) v += __shfl_xor(v, d, 64);
    __shared__ int wsum[4];
    if ((t & 63) == 0) wsum[t >> 6] = v;
    __syncthreads();
    if (t == 0) partials[blockIdx.x] = wsum[0] + wsum[1] + wsum[2] + wsum[3];
}

// ---------------- scan phase 2 (fused): each block derives its chunk prefix from
// partials (wave reduce) then rescans its chunk -> off, cursor. Block 0 writes off[n].
__global__ __launch_bounds__(256) void scan2_kernel(const int* __restrict__ degi,
                                                    const int* __restrict__ partials,
                                                    int* __restrict__ off,
                                                    int* __restrict__ cursor, int n, int nb) {
    int t = threadIdx.x, lane = t & 63, w = t >> 6;
    int c = blockIdx.x;
    // prefix over partials[0..c) + grand total (every wave redundantly)
    int pre = 0, tot = 0;
    for (int base = 0; base < nb; base += 64) {
        int idx = base + lane;
        int pv = (idx < nb) ? partials[idx] : 0;
        pre += (idx < c) ? pv : 0;
        tot += pv;
    }
#pragma unroll
    for (int d = 1; d < 64; d <<= 1) {
        pre += __shfl_xor(pre, d, 64);
        tot += __shfl_xor(tot, d, 64);
    }
    if (c == 0 && t == 0) off[n] = tot;
    // intra-chunk inclusive scan
    int i = c * 256 + t;
    int v = (i < n) ? degi[i] : 0;
    int s = v;
#pragma unroll
    for (int d = 1; d < 64; d <<= 1) {
        int u = __shfl_up(s, d, 64);
        if (lane >= d) s += u;
    }
    __shared__ int wsum[4];
    if (lane == 63) wsum[w] = s;
    __syncthreads();
    int woff = 0;
    for (int k = 0; k < w; ++k) woff += wsum[k];
    int excl = pre + woff + s - v;
    if (i < n) { off[i] = excl; cursor[i] = excl; }
}

// ---------------- CSR fill: eidx[pos] = src[e], pos = cursor[dst[e]]++
__global__ void fill_kernel(const int* __restrict__ src, const int* __restrict__ dst,
                            int* __restrict__ cursor, int* __restrict__ eidx, int n_edges) {
    int e = blockIdx.x * 256 + threadIdx.x;
    if (e < n_edges) {
        int p = atomicAdd(&cursor[dst[e]], 1);
        eidx[p] = src[e];
    }
}

// ---------------- bf16 MFMA GEMM: Y[Mpad,512] = A[Mpad,K] @ BT[512,K]^T (bf16 out)
// 64x128 tile, 4 waves (2x2 of 32x64), BK=64, dbuf global_load_lds, XOR swizzle.
// 1D grid, XCD-aware: the 4 N-tiles sharing an A-stripe get the same b%8 (same XCD).
__global__ __launch_bounds__(256) void gemm_mfma(const ushort* __restrict__ A,
                                                 const ushort* __restrict__ BT,
                                                 ushort* __restrict__ Y, int K, int nG) {
    int b = blockIdx.x;
    int xcd = b & 7, rest = b >> 3;
    int m = rest & 3, Ggrp = rest >> 2;
    int G = xcd + 8 * Ggrp;                    // A-stripe id
    if (G >= nG) return;
    int m0 = G * 64, n0 = m * 128;

    __shared__ ushort As[2][64 * 64];
    __shared__ ushort Bs[2][128 * 64];
    int tid = threadIdx.x;
    int w = tid >> 6, lane = tid & 63;
    int quad = lane >> 4, r16 = lane & 15;
    int wm = (w >> 1) * 32, wn = (w & 1) * 64;

    int arow[2], agu[2], brow[4], bgu[4];
#pragma unroll
    for (int rr = 0; rr < 2; ++rr) {
        int idx = rr * 256 + tid;
        arow[rr] = idx >> 3;
        agu[rr] = (idx & 7) ^ (arow[rr] & 7);
    }
#pragma unroll
    for (int rr = 0; rr < 4; ++rr) {
        int idx = rr * 256 + tid;
        brow[rr] = idx >> 3;
        bgu[rr] = (idx & 7) ^ (brow[rr] & 7);
    }

    auto stage = [&](int buf, int k0) {
#pragma unroll
        for (int rr = 0; rr < 2; ++rr) {
            const ushort* ga = A + (size_t)(m0 + arow[rr]) * K + k0 + agu[rr] * 8;
            ushort* la = As[buf] + (size_t)(rr * 256 + w * 64) * 8;
            __builtin_amdgcn_global_load_lds((gp_t)(const void*)ga, (lp_t)(void*)la, 16, 0, 0);
        }
#pragma unroll
        for (int rr = 0; rr < 4; ++rr) {
            const ushort* gb = BT + (size_t)(n0 + brow[rr]) * K + k0 + bgu[rr] * 8;
            ushort* lb = Bs[buf] + (size_t)(rr * 256 + w * 64) * 8;
            __builtin_amdgcn_global_load_lds((gp_t)(const void*)gb, (lp_t)(void*)lb, 16, 0, 0);
        }
    };

    floatx4 acc[2][4];
#pragma unroll
    for (int i = 0; i < 2; ++i)
#pragma unroll
        for (int j = 0; j < 4; ++j) acc[i][j] = (floatx4){0.f, 0.f, 0.f, 0.f};

    const int nk = K >> 6;
    stage(0, 0);
    for (int t = 0; t < nk; ++t) {
        int cb = t & 1;
        __syncthreads();
        if (t + 1 < nk) stage(cb ^ 1, (t + 1) << 6);
        const ushort* Ab = As[cb];
        const ushort* Bb = Bs[cb];
#pragma unroll
        for (int s = 0; s < 2; ++s) {
            bf16x8 a[2], b2[4];
#pragma unroll
            for (int i = 0; i < 2; ++i) {
                int row = wm + i * 16 + r16;
                int au = (s * 4 + quad) ^ (row & 7);
                a[i] = *(const bf16x8*)(Ab + row * 64 + au * 8);
            }
#pragma unroll
            for (int j = 0; j < 4; ++j) {
                int row = wn + j * 16 + r16;
                int bu = (s * 4 + quad) ^ (row & 7);
                b2[j] = *(const bf16x8*)(Bb + row * 64 + bu * 8);
            }
#pragma unroll
            for (int i = 0; i < 2; ++i)
#pragma unroll
                for (int j = 0; j < 4; ++j)
                    acc[i][j] = __builtin_amdgcn_mfma_f32_16x16x32_bf16(a[i], b2[j], acc[i][j], 0, 0, 0);
        }
    }
#pragma unroll
    for (int i = 0; i < 2; ++i)
#pragma unroll
        for (int j = 0; j < 4; ++j) {
            int col = n0 + wn + j * 16 + r16;
#pragma unroll
            for (int rg = 0; rg < 4; ++rg) {
                int row = m0 + wm + i * 16 + quad * 4 + rg;
                Y[(size_t)row * NCOL + col] = f2bf(acc[i][j][rg]);
            }
        }
}

// ---------------- fused gather + combine: one 64-lane wave per node.
// Coalesced eidx prefetch (lane l gets eidx[e0+l], broadcast via __shfl),
// row loads issued in groups of 8 independent 512B reads.
#define ACC4(A, Yv) { A.x += bf2f(Yv.x); A.y += bf2f(Yv.y); A.z += bf2f(Yv.z); A.w += bf2f(Yv.w); }
__global__ __launch_bounds__(256) void gather_kernel(const ushort* __restrict__ Y,
                                                     const int* __restrict__ off,
                                                     const int* __restrict__ eidx,
                                                     const float* __restrict__ bias,
                                                     ushort* __restrict__ h, int n_nodes) {
    int tid = threadIdx.x;
    int v = blockIdx.x * 4 + (tid >> 6);
    if (v >= n_nodes) return;
    int lane = tid & 63;
    int q4 = lane << 2;
    int e0 = off[v], e1 = off[v + 1];
    ushort4 sv = *(const ushort4*)(Y + (size_t)v * NCOL + HID + q4);   // self (bf16)
    float4 b = *(const float4*)(bias + q4);
    float4 a0 = make_float4(0.f, 0.f, 0.f, 0.f), a1 = a0, a2 = a0, a3 = a0;
    for (int base = e0; base < e1; base += 64) {
        int ecnt = min(64, e1 - base);
        int ev = (lane < ecnt) ? eidx[base + lane] : 0;   // coalesced index prefetch
        int j = 0;
        for (; j + 8 <= ecnt; j += 8) {
            int s0 = __shfl(ev, j + 0), s1 = __shfl(ev, j + 1);
            int s2 = __shfl(ev, j + 2), s3 = __shfl(ev, j + 3);
            int s4 = __shfl(ev, j + 4), s5 = __shfl(ev, j + 5);
            int s6 = __shfl(ev, j + 6), s7 = __shfl(ev, j + 7);
            ushort4 y0 = *(const ushort4*)(Y + (size_t)s0 * NCOL + q4);
            ushort4 y1 = *(const ushort4*)(Y + (size_t)s1 * NCOL + q4);
            ushort4 y2 = *(const ushort4*)(Y + (size_t)s2 * NCOL + q4);
            ushort4 y3 = *(const ushort4*)(Y + (size_t)s3 * NCOL + q4);
            ushort4 y4 = *(const ushort4*)(Y + (size_t)s4 * NCOL + q4);
            ushort4 y5 = *(const ushort4*)(Y + (size_t)s5 * NCOL + q4);
            ushort4 y6 = *(const ushort4*)(Y + (size_t)s6 * NCOL + q4);
            ushort4 y7 = *(const ushort4*)(Y + (size_t)s7 * NCOL + q4);
            ACC4(a0, y0); ACC4(a1, y1); ACC4(a2, y2); ACC4(a3, y3);
            ACC4(a0, y4); ACC4(a1, y5); ACC4(a2, y6); ACC4(a3, y7);
        }
        for (; j < ecnt; ++j) {
            int s = __shfl(ev, j);
            ushort4 y = *(const ushort4*)(Y + (size_t)s * NCOL + q4);
            ACC4(a0, y);
        }
    }
    float invd = 1.0f / fmaxf((float)(e1 - e0), 1.0f);
    ushort4 r;
    r.x = f2bf(fmaxf((a0.x + a1.x + a2.x + a3.x) * invd + bf2f(sv.x) + b.x, 0.f));
    r.y = f2bf(fmaxf((a0.y + a1.y + a2.y + a3.y) * invd + bf2f(sv.y) + b.y, 0.f));
    r.z = f2bf(fmaxf((a0.z + a1.z + a2.z + a3.z) * invd + bf2f(sv.z) + b.z, 0.f));
    r.w = f2bf(fmaxf((a0.w + a1.w + a2.w + a3.w) * invd + bf2f(sv.w) + b.w, 0.f));
    *(ushort4*)(h + (size_t)v * HID + q4) = r;
}

// ---------------- tail: per-graph mean-pool (binary-search segment) + MLP head
__global__ __launch_bounds__(256) void tail_kernel(const ushort* __restrict__ h,
                                                   const int* __restrict__ batch,
                                                   const float* __restrict__ fc1w,
                                                   const float* __restrict__ fc1b,
                                                   const float* __restrict__ fc2w,
                                                   const float* __restrict__ fc2b,
                                                   float* __restrict__ out, int n_nodes) {
    int g = blockIdx.x, t = threadIdx.x;    // 16 blocks x 256 threads
    auto lb = [&](int key) {
        int lo = 0, hi = n_nodes;
        while (lo < hi) { int mid = (lo + hi) >> 1; if (batch[mid] < key) lo = mid + 1; else hi = mid; }
        return lo;
    };
    int lo = lb(g), hi = lb(g + 1);
    float c0 = 0.f, c1 = 0.f, c2 = 0.f, c3 = 0.f;
    int v = lo;
    for (; v + 3 < hi; v += 4) {
        c0 += bf2f(h[(size_t)(v + 0) * HID + t]);
        c1 += bf2f(h[(size_t)(v + 1) * HID + t]);
        c2 += bf2f(h[(size_t)(v + 2) * HID + t]);
        c3 += bf2f(h[(size_t)(v + 3) * HID + t]);
    }
    for (; v < hi; ++v) c0 += bf2f(h[(size_t)v * HID + t]);
    __shared__ float p[256];
    __shared__ float hidv[128];
    float inv = 1.0f / fmaxf((float)(hi - lo), 1.0f);
    p[t] = (c0 + c1 + c2 + c3) * inv;
    __syncthreads();
    if (t < 128) {
        float a = fc1b[t];
        for (int f = 0; f < 256; ++f) a += p[f] * fc1w[f * 128 + t];
        hidv[t] = fmaxf(a, 0.f);
    }
    __syncthreads();
    if (t < 2) {
        float o = fc2b[t];
        for (int k = 0; k < 128; ++k) o += hidv[k] * fc2w[k * 2 + t];
        out[g * 2 + t] = o;
    }
}

extern "C" void kernel_launch(void* const* d_in, const int* in_sizes, int n_in,
                              void* d_out, int out_size, void* d_ws, size_t ws_size,
                              hipStream_t stream) {
    const float* x    = (const float*)d_in[0];
    const int*   ei   = (const int*)d_in[1];
    const int*   batch= (const int*)d_in[2];
    const float* W1n  = (const float*)d_in[3];
    const float* W1s  = (const float*)d_in[4];
    const float* b1   = (const float*)d_in[5];
    const float* W2n  = (const float*)d_in[6];
    const float* W2s  = (const float*)d_in[7];
    const float* b2   = (const float*)d_in[8];
    const float* fc1w = (const float*)d_in[9];
    const float* fc1b = (const float*)d_in[10];
    const float* fc2w = (const float*)d_in[11];
    const float* fc2b = (const float*)d_in[12];
    float* out = (float*)d_out;

    const int n_nodes = in_sizes[2];
    const int n_edges = in_sizes[1] / 2;
    const int in_dim  = in_sizes[0] / n_nodes;   // 512
    const int Mpad    = (n_nodes + 63) & ~63;    // 20032
    const int nb      = (n_nodes + 255) / 256;   // scan chunks (79)
    const int nG      = Mpad / 64;               // A-stripes (313)
    const int* src = ei;
    const int* dst = ei + n_edges;

    // workspace layout, 256B-aligned slices
    char* wsb = (char*)d_ws;
    size_t cur = 0;
    auto alloc = [&](size_t nbytes) { size_t o = cur; cur = (cur + nbytes + 255) & ~(size_t)255; return o; };
    size_t o_degi = alloc((size_t)n_nodes * 4);
    size_t o_off  = alloc((size_t)(n_nodes + 1) * 4);
    size_t o_cur  = alloc((size_t)n_nodes * 4);
    size_t o_part = alloc((size_t)nb * 4);
    size_t o_eidx = alloc((size_t)n_edges * 4);
    size_t o_w1   = alloc((size_t)NCOL * in_dim * 2);
    size_t o_w2   = alloc((size_t)NCOL * HID * 2);
    size_t o_xb   = alloc((size_t)Mpad * in_dim * 2);
    size_t o_hb   = alloc((size_t)Mpad * HID * 2);
    size_t o_y    = alloc((size_t)Mpad * NCOL * 2);
    (void)ws_size;

    int*    degi    = (int*)(wsb + o_degi);
    int*    off     = (int*)(wsb + o_off);
    int*    cursor  = (int*)(wsb + o_cur);
    int*    partials= (int*)(wsb + o_part);
    int*    eidx    = (int*)(wsb + o_eidx);
    ushort* w1t     = (ushort*)(wsb + o_w1);
    ushort* w2t     = (ushort*)(wsb + o_w2);
    ushort* xb      = (ushort*)(wsb + o_xb);
    ushort* hb      = (ushort*)(wsb + o_hb);
    ushort* Y       = (ushort*)(wsb + o_y);

    hipMemsetAsync(degi, 0, (size_t)n_nodes * 4, stream);

    // ---- fused prep: cvt | packT W1 | packT W2 | degree histogram
    int n4 = n_nodes * in_dim / 4;
    int nb_cvt = (n4 + 255) / 256;
    int nb_w1  = (NCOL * in_dim + 255) / 256;
    int nb_w2  = (NCOL * HID + 255) / 256;
    int nb_deg = (n_edges + 255) / 256;
    prep_kernel<<<nb_cvt + nb_w1 + nb_w2 + nb_deg, 256, 0, stream>>>(
        x, xb, n4, W1n, W1s, w1t, in_dim, W2n, W2s, w2t, HID,
        dst, degi, n_edges, nb_cvt, nb_w1, nb_w2);

    // ---- CSR build: chunk sums -> fused prefix+rescan -> fill
    psum_kernel<<<nb, 256, 0, stream>>>(degi, partials, n_nodes);
    scan2_kernel<<<nb, 256, 0, stream>>>(degi, partials, off, cursor, n_nodes, nb);
    fill_kernel<<<(n_edges + 255) / 256, 256, 0, stream>>>(src, dst, cursor, eidx, n_edges);

    // XCD-grouped 1D gemm grid
    int gemm_blocks = 8 * 4 * ((nG + 7) / 8);
    int gather_blocks = (n_nodes + 3) / 4;

    // ---- layer 1
    gemm_mfma<<<gemm_blocks, 256, 0, stream>>>(xb, w1t, Y, in_dim, nG);
    gather_kernel<<<gather_blocks, 256, 0, stream>>>(Y, off, eidx, b1, hb, n_nodes);

    // ---- layer 2
    gemm_mfma<<<gemm_blocks, 256, 0, stream>>>(hb, w2t, Y, HID, nG);
    gather_kernel<<<gather_blocks, 256, 0, stream>>>(Y, off, eidx, b2, hb, n_nodes);

    // ---- fused pool + head
    tail_kernel<<<16, 256, 0, stream>>>(hb, batch, fc1w, fc1b, fc2w, fc2b, out, n_nodes);
}

// Round 11
// 223.425 us; speedup vs baseline: 1.3028x; 1.3028x over previous
//
#include <hip/hip_runtime.h>
#include <hip/hip_bf16.h>

// GraphSAGE forward. R10: keep R9's gather (coalesced eidx prefetch, 8-deep
// row pipelining) + fused scan; revert R9's 16-block tail fusion (105us,
// 6% CU utilization) back to parallel pool_kernel (313 blocks) + head_kernel.

#define HID 256
#define NCOL 512

typedef __bf16 bf16x8 __attribute__((ext_vector_type(8)));
typedef float floatx4 __attribute__((ext_vector_type(4)));
typedef unsigned int u32;
typedef const u32 __attribute__((address_space(1)))* gp_t;
typedef u32 __attribute__((address_space(3)))* lp_t;

__device__ __forceinline__ ushort f2bf(float f) {   // round-to-nearest-even
    unsigned u = __float_as_uint(f);
    u += 0x7fffu + ((u >> 16) & 1u);
    return (ushort)(u >> 16);
}
__device__ __forceinline__ float bf2f(ushort b) {
    return __uint_as_float(((unsigned)b) << 16);
}

// ---------------- fused prep: [cvt x->bf16 | packT W1 | packT W2 | degree histogram]
__device__ __forceinline__ void packT_work(const float* __restrict__ Wn,
                                           const float* __restrict__ Ws,
                                           ushort* __restrict__ WT, int K, int gid) {
    if (gid >= NCOL * K) return;
    int n = gid / K, k = gid - n * K;
    float v = (n < HID) ? Wn[k * HID + n] : Ws[k * HID + (n - HID)];
    WT[gid] = f2bf(v);
}

__global__ void prep_kernel(const float* __restrict__ x, ushort* __restrict__ xb, int n4,
                            const float* __restrict__ W1n, const float* __restrict__ W1s,
                            ushort* __restrict__ w1t, int K1,
                            const float* __restrict__ W2n, const float* __restrict__ W2s,
                            ushort* __restrict__ w2t, int K2,
                            const int* __restrict__ dst, int* __restrict__ degi, int n_edges,
                            int nb_cvt, int nb_w1, int nb_w2) {
    int bx = blockIdx.x, t = threadIdx.x;
    if (bx < nb_cvt) {
        int i = bx * 256 + t;
        if (i < n4) {
            float4 v = ((const float4*)x)[i];
            ushort4 o;
            o.x = f2bf(v.x); o.y = f2bf(v.y); o.z = f2bf(v.z); o.w = f2bf(v.w);
            ((ushort4*)xb)[i] = o;
        }
    } else if (bx < nb_cvt + nb_w1) {
        packT_work(W1n, W1s, w1t, K1, (bx - nb_cvt) * 256 + t);
    } else if (bx < nb_cvt + nb_w1 + nb_w2) {
        packT_work(W2n, W2s, w2t, K2, (bx - nb_cvt - nb_w1) * 256 + t);
    } else {
        int e = (bx - nb_cvt - nb_w1 - nb_w2) * 256 + t;
        if (e < n_edges) atomicAdd(&degi[dst[e]], 1);
    }
}

// ---------------- scan phase 1: per-256-chunk sums
__global__ __launch_bounds__(256) void psum_kernel(const int* __restrict__ degi,
                                                   int* __restrict__ partials, int n) {
    int t = threadIdx.x;
    int i = blockIdx.x * 256 + t;
    int v = (i < n) ? degi[i] : 0;
#pragma unroll
    for (int d = 1; d < 64; d <<= 1) v += __shfl_xor(v, d, 64);
    __shared__ int wsum[4];
    if ((t & 63) == 0) wsum[t >> 6] = v;
    __syncthreads();
    if (t == 0) partials[blockIdx.x] = wsum[0] + wsum[1] + wsum[2] + wsum[3];
}

// ---------------- scan phase 2 (fused): each block derives its chunk prefix from
// partials (wave reduce) then rescans its chunk -> off, cursor. Block 0 writes off[n].
__global__ __launch_bounds__(256) void scan2_kernel(const int* __restrict__ degi,
                                                    const int* __restrict__ partials,
                                                    int* __restrict__ off,
                                                    int* __restrict__ cursor, int n, int nb) {
    int t = threadIdx.x, lane = t & 63, w = t >> 6;
    int c = blockIdx.x;
    int pre = 0, tot = 0;
    for (int base = 0; base < nb; base += 64) {
        int idx = base + lane;
        int pv = (idx < nb) ? partials[idx] : 0;
        pre += (idx < c) ? pv : 0;
        tot += pv;
    }
#pragma unroll
    for (int d = 1; d < 64; d <<= 1) {
        pre += __shfl_xor(pre, d, 64);
        tot += __shfl_xor(tot, d, 64);
    }
    if (c == 0 && t == 0) off[n] = tot;
    int i = c * 256 + t;
    int v = (i < n) ? degi[i] : 0;
    int s = v;
#pragma unroll
    for (int d = 1; d < 64; d <<= 1) {
        int u = __shfl_up(s, d, 64);
        if (lane >= d) s += u;
    }
    __shared__ int wsum[4];
    if (lane == 63) wsum[w] = s;
    __syncthreads();
    int woff = 0;
    for (int k = 0; k < w; ++k) woff += wsum[k];
    int excl = pre + woff + s - v;
    if (i < n) { off[i] = excl; cursor[i] = excl; }
}

// ---------------- CSR fill: eidx[pos] = src[e], pos = cursor[dst[e]]++
__global__ void fill_kernel(const int* __restrict__ src, const int* __restrict__ dst,
                            int* __restrict__ cursor, int* __restrict__ eidx, int n_edges) {
    int e = blockIdx.x * 256 + threadIdx.x;
    if (e < n_edges) {
        int p = atomicAdd(&cursor[dst[e]], 1);
        eidx[p] = src[e];
    }
}

// ---------------- bf16 MFMA GEMM: Y[Mpad,512] = A[Mpad,K] @ BT[512,K]^T (bf16 out)
// 64x128 tile, 4 waves (2x2 of 32x64), BK=64, dbuf global_load_lds, XOR swizzle.
// 1D grid, XCD-aware: the 4 N-tiles sharing an A-stripe get the same b%8 (same XCD).
__global__ __launch_bounds__(256) void gemm_mfma(const ushort* __restrict__ A,
                                                 const ushort* __restrict__ BT,
                                                 ushort* __restrict__ Y, int K, int nG) {
    int b = blockIdx.x;
    int xcd = b & 7, rest = b >> 3;
    int m = rest & 3, Ggrp = rest >> 2;
    int G = xcd + 8 * Ggrp;                    // A-stripe id
    if (G >= nG) return;
    int m0 = G * 64, n0 = m * 128;

    __shared__ ushort As[2][64 * 64];
    __shared__ ushort Bs[2][128 * 64];
    int tid = threadIdx.x;
    int w = tid >> 6, lane = tid & 63;
    int quad = lane >> 4, r16 = lane & 15;
    int wm = (w >> 1) * 32, wn = (w & 1) * 64;

    int arow[2], agu[2], brow[4], bgu[4];
#pragma unroll
    for (int rr = 0; rr < 2; ++rr) {
        int idx = rr * 256 + tid;
        arow[rr] = idx >> 3;
        agu[rr] = (idx & 7) ^ (arow[rr] & 7);
    }
#pragma unroll
    for (int rr = 0; rr < 4; ++rr) {
        int idx = rr * 256 + tid;
        brow[rr] = idx >> 3;
        bgu[rr] = (idx & 7) ^ (brow[rr] & 7);
    }

    auto stage = [&](int buf, int k0) {
#pragma unroll
        for (int rr = 0; rr < 2; ++rr) {
            const ushort* ga = A + (size_t)(m0 + arow[rr]) * K + k0 + agu[rr] * 8;
            ushort* la = As[buf] + (size_t)(rr * 256 + w * 64) * 8;
            __builtin_amdgcn_global_load_lds((gp_t)(const void*)ga, (lp_t)(void*)la, 16, 0, 0);
        }
#pragma unroll
        for (int rr = 0; rr < 4; ++rr) {
            const ushort* gb = BT + (size_t)(n0 + brow[rr]) * K + k0 + bgu[rr] * 8;
            ushort* lb = Bs[buf] + (size_t)(rr * 256 + w * 64) * 8;
            __builtin_amdgcn_global_load_lds((gp_t)(const void*)gb, (lp_t)(void*)lb, 16, 0, 0);
        }
    };

    floatx4 acc[2][4];
#pragma unroll
    for (int i = 0; i < 2; ++i)
#pragma unroll
        for (int j = 0; j < 4; ++j) acc[i][j] = (floatx4){0.f, 0.f, 0.f, 0.f};

    const int nk = K >> 6;
    stage(0, 0);
    for (int t = 0; t < nk; ++t) {
        int cb = t & 1;
        __syncthreads();
        if (t + 1 < nk) stage(cb ^ 1, (t + 1) << 6);
        const ushort* Ab = As[cb];
        const ushort* Bb = Bs[cb];
#pragma unroll
        for (int s = 0; s < 2; ++s) {
            bf16x8 a[2], b2[4];
#pragma unroll
            for (int i = 0; i < 2; ++i) {
                int row = wm + i * 16 + r16;
                int au = (s * 4 + quad) ^ (row & 7);
                a[i] = *(const bf16x8*)(Ab + row * 64 + au * 8);
            }
#pragma unroll
            for (int j = 0; j < 4; ++j) {
                int row = wn + j * 16 + r16;
                int bu = (s * 4 + quad) ^ (row & 7);
                b2[j] = *(const bf16x8*)(Bb + row * 64 + bu * 8);
            }
#pragma unroll
            for (int i = 0; i < 2; ++i)
#pragma unroll
                for (int j = 0; j < 4; ++j)
                    acc[i][j] = __builtin_amdgcn_mfma_f32_16x16x32_bf16(a[i], b2[j], acc[i][j], 0, 0, 0);
        }
    }
#pragma unroll
    for (int i = 0; i < 2; ++i)
#pragma unroll
        for (int j = 0; j < 4; ++j) {
            int col = n0 + wn + j * 16 + r16;
#pragma unroll
            for (int rg = 0; rg < 4; ++rg) {
                int row = m0 + wm + i * 16 + quad * 4 + rg;
                Y[(size_t)row * NCOL + col] = f2bf(acc[i][j][rg]);
            }
        }
}

// ---------------- fused gather + combine: one 64-lane wave per node.
// Coalesced eidx prefetch (lane l gets eidx[e0+l], broadcast via __shfl),
// row loads issued in groups of 8 independent 512B reads.
#define ACC4(A, Yv) { A.x += bf2f(Yv.x); A.y += bf2f(Yv.y); A.z += bf2f(Yv.z); A.w += bf2f(Yv.w); }
__global__ __launch_bounds__(256) void gather_kernel(const ushort* __restrict__ Y,
                                                     const int* __restrict__ off,
                                                     const int* __restrict__ eidx,
                                                     const float* __restrict__ bias,
                                                     ushort* __restrict__ h, int n_nodes) {
    int tid = threadIdx.x;
    int v = blockIdx.x * 4 + (tid >> 6);
    if (v >= n_nodes) return;
    int lane = tid & 63;
    int q4 = lane << 2;
    int e0 = off[v], e1 = off[v + 1];
    ushort4 sv = *(const ushort4*)(Y + (size_t)v * NCOL + HID + q4);   // self (bf16)
    float4 b = *(const float4*)(bias + q4);
    float4 a0 = make_float4(0.f, 0.f, 0.f, 0.f), a1 = a0, a2 = a0, a3 = a0;
    for (int base = e0; base < e1; base += 64) {
        int ecnt = min(64, e1 - base);
        int ev = (lane < ecnt) ? eidx[base + lane] : 0;   // coalesced index prefetch
        int j = 0;
        for (; j + 8 <= ecnt; j += 8) {
            int s0 = __shfl(ev, j + 0), s1 = __shfl(ev, j + 1);
            int s2 = __shfl(ev, j + 2), s3 = __shfl(ev, j + 3);
            int s4 = __shfl(ev, j + 4), s5 = __shfl(ev, j + 5);
            int s6 = __shfl(ev, j + 6), s7 = __shfl(ev, j + 7);
            ushort4 y0 = *(const ushort4*)(Y + (size_t)s0 * NCOL + q4);
            ushort4 y1 = *(const ushort4*)(Y + (size_t)s1 * NCOL + q4);
            ushort4 y2 = *(const ushort4*)(Y + (size_t)s2 * NCOL + q4);
            ushort4 y3 = *(const ushort4*)(Y + (size_t)s3 * NCOL + q4);
            ushort4 y4 = *(const ushort4*)(Y + (size_t)s4 * NCOL + q4);
            ushort4 y5 = *(const ushort4*)(Y + (size_t)s5 * NCOL + q4);
            ushort4 y6 = *(const ushort4*)(Y + (size_t)s6 * NCOL + q4);
            ushort4 y7 = *(const ushort4*)(Y + (size_t)s7 * NCOL + q4);
            ACC4(a0, y0); ACC4(a1, y1); ACC4(a2, y2); ACC4(a3, y3);
            ACC4(a0, y4); ACC4(a1, y5); ACC4(a2, y6); ACC4(a3, y7);
        }
        for (; j < ecnt; ++j) {
            int s = __shfl(ev, j);
            ushort4 y = *(const ushort4*)(Y + (size_t)s * NCOL + q4);
            ACC4(a0, y);
        }
    }
    float invd = 1.0f / fmaxf((float)(e1 - e0), 1.0f);
    ushort4 r;
    r.x = f2bf(fmaxf((a0.x + a1.x + a2.x + a3.x) * invd + bf2f(sv.x) + b.x, 0.f));
    r.y = f2bf(fmaxf((a0.y + a1.y + a2.y + a3.y) * invd + bf2f(sv.y) + b.y, 0.f));
    r.z = f2bf(fmaxf((a0.z + a1.z + a2.z + a3.z) * invd + bf2f(sv.z) + b.z, 0.f));
    r.w = f2bf(fmaxf((a0.w + a1.w + a2.w + a3.w) * invd + bf2f(sv.w) + b.w, 0.f));
    *(ushort4*)(h + (size_t)v * HID + q4) = r;
}

// ---------------- segmented mean-pool (batch sorted), bf16 in, fp32 accumulate
__global__ void pool_kernel(const ushort* __restrict__ h, const int* __restrict__ batch,
                            float* __restrict__ pooled, float* __restrict__ cnt, int n_nodes) {
    int f = threadIdx.x;                     // 256 features
    int v0 = blockIdx.x * 64;
    int vend = min(v0 + 64, n_nodes);
    if (v0 >= n_nodes) return;
    int cur = batch[v0];
    float acc = 0.f, ac = 0.f;
    for (int v = v0; v < vend; ++v) {
        int g = batch[v];
        if (g != cur) {
            atomicAdd(&pooled[cur * HID + f], acc);
            if (f == 0) atomicAdd(&cnt[cur], ac);
            acc = 0.f; ac = 0.f; cur = g;
        }
        acc += bf2f(h[(size_t)v * HID + f]);
        ac += 1.0f;
    }
    atomicAdd(&pooled[cur * HID + f], acc);
    if (f == 0) atomicAdd(&cnt[cur], ac);
}

// ---------------- MLP head: out[g] = relu(pooled_mean @ fc1w + fc1b) @ fc2w + fc2b
__global__ void head_kernel(const float* __restrict__ pooled, const float* __restrict__ cnt,
                            const float* __restrict__ fc1w, const float* __restrict__ fc1b,
                            const float* __restrict__ fc2w, const float* __restrict__ fc2b,
                            float* __restrict__ out) {
    int g = blockIdx.x, j = threadIdx.x;     // 128 threads
    __shared__ float p[256];
    __shared__ float hid[128];
    float inv = 1.0f / fmaxf(cnt[g], 1.0f);
    p[j] = pooled[g * HID + j] * inv;
    p[j + 128] = pooled[g * HID + 128 + j] * inv;
    __syncthreads();
    float a = fc1b[j];
    for (int f = 0; f < 256; ++f) a += p[f] * fc1w[f * 128 + j];
    hid[j] = fmaxf(a, 0.f);
    __syncthreads();
    if (j < 2) {
        float o = fc2b[j];
        for (int t = 0; t < 128; ++t) o += hid[t] * fc2w[t * 2 + j];
        out[g * 2 + j] = o;
    }
}

extern "C" void kernel_launch(void* const* d_in, const int* in_sizes, int n_in,
                              void* d_out, int out_size, void* d_ws, size_t ws_size,
                              hipStream_t stream) {
    const float* x    = (const float*)d_in[0];
    const int*   ei   = (const int*)d_in[1];
    const int*   batch= (const int*)d_in[2];
    const float* W1n  = (const float*)d_in[3];
    const float* W1s  = (const float*)d_in[4];
    const float* b1   = (const float*)d_in[5];
    const float* W2n  = (const float*)d_in[6];
    const float* W2s  = (const float*)d_in[7];
    const float* b2   = (const float*)d_in[8];
    const float* fc1w = (const float*)d_in[9];
    const float* fc1b = (const float*)d_in[10];
    const float* fc2w = (const float*)d_in[11];
    const float* fc2b = (const float*)d_in[12];
    float* out = (float*)d_out;

    const int n_nodes = in_sizes[2];
    const int n_edges = in_sizes[1] / 2;
    const int in_dim  = in_sizes[0] / n_nodes;   // 512
    const int Mpad    = (n_nodes + 63) & ~63;    // 20032
    const int nb      = (n_nodes + 255) / 256;   // scan chunks (79)
    const int nG      = Mpad / 64;               // A-stripes (313)
    const int* src = ei;
    const int* dst = ei + n_edges;

    // workspace layout, 256B-aligned slices
    char* wsb = (char*)d_ws;
    size_t cur = 0;
    auto alloc = [&](size_t nbytes) { size_t o = cur; cur = (cur + nbytes + 255) & ~(size_t)255; return o; };
    size_t o_degi = alloc((size_t)n_nodes * 4);
    size_t o_off  = alloc((size_t)(n_nodes + 1) * 4);
    size_t o_cur  = alloc((size_t)n_nodes * 4);
    size_t o_part = alloc((size_t)nb * 4);
    size_t o_eidx = alloc((size_t)n_edges * 4);
    size_t o_w1   = alloc((size_t)NCOL * in_dim * 2);
    size_t o_w2   = alloc((size_t)NCOL * HID * 2);
    size_t o_xb   = alloc((size_t)Mpad * in_dim * 2);
    size_t o_hb   = alloc((size_t)Mpad * HID * 2);
    size_t o_y    = alloc((size_t)Mpad * NCOL * 2);
    size_t o_pool = alloc((size_t)16 * HID * 4 + 16 * 4);
    (void)ws_size;

    int*    degi    = (int*)(wsb + o_degi);
    int*    off     = (int*)(wsb + o_off);
    int*    cursor  = (int*)(wsb + o_cur);
    int*    partials= (int*)(wsb + o_part);
    int*    eidx    = (int*)(wsb + o_eidx);
    ushort* w1t     = (ushort*)(wsb + o_w1);
    ushort* w2t     = (ushort*)(wsb + o_w2);
    ushort* xb      = (ushort*)(wsb + o_xb);
    ushort* hb      = (ushort*)(wsb + o_hb);
    ushort* Y       = (ushort*)(wsb + o_y);
    float*  pooled  = (float*)(wsb + o_pool);
    float*  cnt     = pooled + 16 * HID;

    hipMemsetAsync(degi, 0, (size_t)n_nodes * 4, stream);
    hipMemsetAsync(pooled, 0, (size_t)(16 * HID + 16) * 4, stream);

    // ---- fused prep: cvt | packT W1 | packT W2 | degree histogram
    int n4 = n_nodes * in_dim / 4;
    int nb_cvt = (n4 + 255) / 256;
    int nb_w1  = (NCOL * in_dim + 255) / 256;
    int nb_w2  = (NCOL * HID + 255) / 256;
    int nb_deg = (n_edges + 255) / 256;
    prep_kernel<<<nb_cvt + nb_w1 + nb_w2 + nb_deg, 256, 0, stream>>>(
        x, xb, n4, W1n, W1s, w1t, in_dim, W2n, W2s, w2t, HID,
        dst, degi, n_edges, nb_cvt, nb_w1, nb_w2);

    // ---- CSR build: chunk sums -> fused prefix+rescan -> fill
    psum_kernel<<<nb, 256, 0, stream>>>(degi, partials, n_nodes);
    scan2_kernel<<<nb, 256, 0, stream>>>(degi, partials, off, cursor, n_nodes, nb);
    fill_kernel<<<(n_edges + 255) / 256, 256, 0, stream>>>(src, dst, cursor, eidx, n_edges);

    // XCD-grouped 1D gemm grid
    int gemm_blocks = 8 * 4 * ((nG + 7) / 8);
    int gather_blocks = (n_nodes + 3) / 4;

    // ---- layer 1
    gemm_mfma<<<gemm_blocks, 256, 0, stream>>>(xb, w1t, Y, in_dim, nG);
    gather_kernel<<<gather_blocks, 256, 0, stream>>>(Y, off, eidx, b1, hb, n_nodes);

    // ---- layer 2
    gemm_mfma<<<gemm_blocks, 256, 0, stream>>>(hb, w2t, Y, HID, nG);
    gather_kernel<<<gather_blocks, 256, 0, stream>>>(Y, off, eidx, b2, hb, n_nodes);

    // ---- pool + head
    pool_kernel<<<(n_nodes + 63) / 64, 256, 0, stream>>>(hb, batch, pooled, cnt, n_nodes);
    head_kernel<<<16, 128, 0, stream>>>(pooled, cnt, fc1w, fc1b, fc2w, fc2b, out);
}